// Round 5
// baseline (1897.730 us; speedup 1.0000x reference)
//
#include <hip/hip_runtime.h>
#include <cstdint>
#include <cstddef>

#define HID 512
#define BATCH 4096
#define T_STEPS 20
#define NSTEP (T_STEPS - 1)
#define ROWS 16          // batch rows per block
#define LDST 520         // LDS row stride (elements) — breaks pow2 banking

typedef unsigned short ushort_t;
typedef __attribute__((ext_vector_type(8))) __bf16 bf16x8;
typedef __attribute__((ext_vector_type(4))) float f32x4;

// fp32 -> bf16 round-to-nearest-even (finite inputs only)
__device__ __forceinline__ unsigned short f2bf(float f) {
  unsigned int u = __float_as_uint(f);
  u += 0x7FFFu + ((u >> 16) & 1u);
  return (unsigned short)(u >> 16);
}

__device__ __forceinline__ float wave_max(float v) {
#pragma unroll
  for (int off = 32; off > 0; off >>= 1) v = fmaxf(v, __shfl_xor(v, off));
  return v;
}
__device__ __forceinline__ float wave_sum(float v) {
#pragma unroll
  for (int off = 32; off > 0; off >>= 1) v += __shfl_xor(v, off);
  return v;
}

// ---------------------------------------------------------------------------
// weights fp32 -> bf16. Wcat2 gate-interleaved [1536,512]: packed row p:
// group=p/48, within=p%48, gate=within/16, hh=group*16+(within&15).
// WoutB plain [512,512].
// ---------------------------------------------------------------------------
__global__ __launch_bounds__(256) void convw_kernel(
    const float* __restrict__ Wi, const float* __restrict__ Wg,
    const float* __restrict__ Wo, const float* __restrict__ Wout,
    ushort_t* __restrict__ Wcat2, ushort_t* __restrict__ WoutB) {
  const int t = blockIdx.x * 256 + threadIdx.x;  // 1024 x 256 = 262144
  const float* src;
  ushort_t* dst;
  if (t < 196608) {
    int prow = t >> 7;
    int kk = (t & 127) * 4;
    int group = prow / 48;
    int within = prow % 48;
    int gate = within >> 4;
    int hh = group * 16 + (within & 15);
    src = (gate == 0 ? Wi : gate == 1 ? Wg : Wo) + (size_t)hh * HID + kk;
    dst = Wcat2 + (size_t)prow * HID + kk;
  } else {
    int t2 = t - 196608;
    int row = t2 >> 7;
    int kk = (t2 & 127) * 4;
    src = Wout + (size_t)row * HID + kk;
    dst = WoutB + (size_t)row * HID + kk;
  }
  float4 v = *(const float4*)src;
  union { unsigned short us[4]; uint2 u; } p;
  p.us[0] = f2bf(v.x); p.us[1] = f2bf(v.y); p.us[2] = f2bf(v.z); p.us[3] = f2bf(v.w);
  *(uint2*)dst = p.u;
}

// ---------------------------------------------------------------------------
// Persistent row-local kernel: block owns ROWS=16 batch rows for all 19 steps.
// z, zb, dh live in LDS only. Weights streamed global(L2)->VGPR each step.
// 512 threads = 8 waves. Gate phase: wave w handles packed cols [w*192,w*192+192)
// = 4 h-groups of 48 (16 i |16 g |16 o). Out phase: wave w owns out cols
// [w*64, w*64+64). 16x16x32 bf16 MFMA; A-frags from LDS (m=lane&15,
// k=quad*8+j); C/D layout col=lane&15, row=quad*4+reg (m89-verified).
// ---------------------------------------------------------------------------
__global__ __launch_bounds__(512, 2) void persist_kernel(
    const float* __restrict__ y, const float* __restrict__ ts,
    const float* __restrict__ bout, const float* __restrict__ Wfc,
    const float* __restrict__ bfc, const ushort_t* __restrict__ Wcat2,
    const ushort_t* __restrict__ WoutB, float* __restrict__ out) {
  __shared__ float z_lds[ROWS * LDST];        // 33280 B
  __shared__ ushort_t zb_lds[ROWS * LDST];    // 16640 B
  __shared__ ushort_t dh_lds[ROWS * LDST];    // 16640 B
  __shared__ float redm[8 * 16];
  __shared__ float redA[8 * 16];
  __shared__ float redB[8 * 16];

  const int tid = threadIdx.x;
  const int wave = tid >> 6;
  const int lane = tid & 63;
  const int quad = lane >> 4;
  const int l16 = lane & 15;
  const int b0 = blockIdx.x * ROWS;
  const int wn = wave * 64;
  const float bfc0 = bfc[0];

  // per-wave column constants for the out phase
  float bo4[4], wf4[4];
#pragma unroll
  for (int j = 0; j < 4; ++j) {
    bo4[j] = bout[wn + j * 16 + l16];
    wf4[j] = Wfc[wn + j * 16 + l16];
  }

  // ---- init: z=y, zb=bf16(y), out[:,0]=softmax(y)·Wfc+bfc (wave: 2 rows) ----
#pragma unroll
  for (int rr = 0; rr < 2; ++rr) {
    const int lrow = wave * 2 + rr;
    const float4* y4 = (const float4*)(y + (size_t)(b0 + lrow) * HID);
    float4 v0 = y4[lane * 2];
    float4 v1 = y4[lane * 2 + 1];
    float zn[8] = {v0.x, v0.y, v0.z, v0.w, v1.x, v1.y, v1.z, v1.w};
    *(float4*)&z_lds[lrow * LDST + lane * 8] = v0;
    *(float4*)&z_lds[lrow * LDST + lane * 8 + 4] = v1;
    union { unsigned short us[8]; uint4 v; } p;
#pragma unroll
    for (int i = 0; i < 8; ++i) p.us[i] = f2bf(zn[i]);
    *(uint4*)&zb_lds[lrow * LDST + lane * 8] = p.v;

    const float4* w4 = (const float4*)Wfc;
    float4 w0 = w4[lane * 2], w1 = w4[lane * 2 + 1];
    float w[8] = {w0.x, w0.y, w0.z, w0.w, w1.x, w1.y, w1.z, w1.w};
    float m = zn[0];
#pragma unroll
    for (int i = 1; i < 8; ++i) m = fmaxf(m, zn[i]);
    m = wave_max(m);
    float s = 0.f, d = 0.f;
#pragma unroll
    for (int i = 0; i < 8; ++i) { float e = expf(zn[i] - m); s += e; d += e * w[i]; }
    s = wave_sum(s);
    d = wave_sum(d);
    if (lane == 0) out[(size_t)(b0 + lrow) * T_STEPS] = d / s + bfc0;
  }
  __syncthreads();

  // ---- 19 Euler steps, no global state, no grid sync ----
  for (int t = 0; t < NSTEP; ++t) {
    const float dt = ts[t + 1] - ts[t];

    // A-fragments: zb rows (m=l16), all K; held in regs for whole gate phase
    bf16x8 af[16];
#pragma unroll
    for (int ks = 0; ks < 16; ++ks)
      af[ks] = *(const bf16x8*)&zb_lds[l16 * LDST + ks * 32 + quad * 8];

    // gate GEMM + activation: 4 h-groups of (i,g,o) 16-col tiles
#pragma unroll
    for (int hg = 0; hg < 4; ++hg) {
      const ushort_t* Bp = Wcat2 + (size_t)(wave * 192 + hg * 48 + l16) * HID;
      f32x4 ga[3] = {};
#pragma unroll 4
      for (int ks = 0; ks < 16; ++ks) {
        bf16x8 bi = *(const bf16x8*)(Bp + ks * 32 + quad * 8);
        bf16x8 bg = *(const bf16x8*)(Bp + 16 * HID + ks * 32 + quad * 8);
        bf16x8 bo = *(const bf16x8*)(Bp + 32 * HID + ks * 32 + quad * 8);
        ga[0] = __builtin_amdgcn_mfma_f32_16x16x32_bf16(af[ks], bi, ga[0], 0, 0, 0);
        ga[1] = __builtin_amdgcn_mfma_f32_16x16x32_bf16(af[ks], bg, ga[1], 0, 0, 0);
        ga[2] = __builtin_amdgcn_mfma_f32_16x16x32_bf16(af[ks], bo, ga[2], 0, 0, 0);
      }
      const int hb = wave * 64 + hg * 16;
#pragma unroll
      for (int r = 0; r < 4; ++r) {
        float si = 1.f / (1.f + expf(-ga[0][r]));
        float tg = tanhf(ga[1][r]);
        float so = 1.f / (1.f + expf(-ga[2][r]));
        dh_lds[(quad * 4 + r) * LDST + hb + l16] = f2bf(so * tanhf(si * tg));
      }
    }
    __syncthreads();  // dh complete

    // out GEMM: wave owns 64 cols; A-frags from dh
    bf16x8 ad[16];
#pragma unroll
    for (int ks = 0; ks < 16; ++ks)
      ad[ks] = *(const bf16x8*)&dh_lds[l16 * LDST + ks * 32 + quad * 8];
    f32x4 c[4] = {};
#pragma unroll
    for (int j = 0; j < 4; ++j) {
      const ushort_t* Bw = WoutB + (size_t)(wn + j * 16 + l16) * HID;
#pragma unroll 4
      for (int ks = 0; ks < 16; ++ks)
        c[j] = __builtin_amdgcn_mfma_f32_16x16x32_bf16(
            ad[ks], *(const bf16x8*)(Bw + ks * 32 + quad * 8), c[j], 0, 0, 0);
    }

    // + bout
#pragma unroll
    for (int j = 0; j < 4; ++j)
#pragma unroll
      for (int r = 0; r < 4; ++r) c[j][r] += bo4[j];

    // softmax #1: max over 512 cols (j-regs, l16 lanes, 8 waves)
    float mr[4];
#pragma unroll
    for (int r = 0; r < 4; ++r) {
      float pm = fmaxf(fmaxf(c[0][r], c[1][r]), fmaxf(c[2][r], c[3][r]));
#pragma unroll
      for (int off = 1; off < 16; off <<= 1) pm = fmaxf(pm, __shfl_xor(pm, off));
      mr[r] = pm;
    }
    if (l16 == 0) {
#pragma unroll
      for (int r = 0; r < 4; ++r) redm[wave * 16 + quad * 4 + r] = mr[r];
    }
    __syncthreads();
#pragma unroll
    for (int r = 0; r < 4; ++r) {
      float m = redm[quad * 4 + r];
#pragma unroll
      for (int w = 1; w < 8; ++w) m = fmaxf(m, redm[w * 16 + quad * 4 + r]);
      mr[r] = m;
    }
    __syncthreads();

    // exp (in place) + sum
    float inv[4];
#pragma unroll
    for (int r = 0; r < 4; ++r) {
      float ps = 0.f;
#pragma unroll
      for (int j = 0; j < 4; ++j) {
        c[j][r] = expf(c[j][r] - mr[r]);
        ps += c[j][r];
      }
#pragma unroll
      for (int off = 1; off < 16; off <<= 1) ps += __shfl_xor(ps, off);
      inv[r] = ps;
    }
    if (l16 == 0) {
#pragma unroll
      for (int r = 0; r < 4; ++r) redm[wave * 16 + quad * 4 + r] = inv[r];
    }
    __syncthreads();
#pragma unroll
    for (int r = 0; r < 4; ++r) {
      float s = 0.f;
#pragma unroll
      for (int w = 0; w < 8; ++w) s += redm[w * 16 + quad * 4 + r];
      inv[r] = 1.f / s;
    }
    __syncthreads();

    // z += dt*softmax ; refresh zb ; c becomes z_new
#pragma unroll
    for (int r = 0; r < 4; ++r) {
      const int row = quad * 4 + r;
#pragma unroll
      for (int j = 0; j < 4; ++j) {
        const int idx = row * LDST + wn + j * 16 + l16;
        float v = z_lds[idx] + dt * c[j][r] * inv[r];
        z_lds[idx] = v;
        zb_lds[idx] = f2bf(v);
        c[j][r] = v;
      }
    }

    // softmax #2 over z_new + readout dot
    float mr2[4];
#pragma unroll
    for (int r = 0; r < 4; ++r) {
      float pm = fmaxf(fmaxf(c[0][r], c[1][r]), fmaxf(c[2][r], c[3][r]));
#pragma unroll
      for (int off = 1; off < 16; off <<= 1) pm = fmaxf(pm, __shfl_xor(pm, off));
      mr2[r] = pm;
    }
    if (l16 == 0) {
#pragma unroll
      for (int r = 0; r < 4; ++r) redm[wave * 16 + quad * 4 + r] = mr2[r];
    }
    __syncthreads();
#pragma unroll
    for (int r = 0; r < 4; ++r) {
      float m = redm[quad * 4 + r];
#pragma unroll
      for (int w = 1; w < 8; ++w) m = fmaxf(m, redm[w * 16 + quad * 4 + r]);
      mr2[r] = m;
    }
    __syncthreads();

#pragma unroll
    for (int r = 0; r < 4; ++r) {
      float ps = 0.f, pd = 0.f;
#pragma unroll
      for (int j = 0; j < 4; ++j) {
        float e = expf(c[j][r] - mr2[r]);
        ps += e;
        pd += e * wf4[j];
      }
#pragma unroll
      for (int off = 1; off < 16; off <<= 1) {
        ps += __shfl_xor(ps, off);
        pd += __shfl_xor(pd, off);
      }
      if (l16 == 0) {
        redA[wave * 16 + quad * 4 + r] = ps;
        redB[wave * 16 + quad * 4 + r] = pd;
      }
    }
    __syncthreads();
    if (tid < 16) {
      float s = 0.f, d = 0.f;
#pragma unroll
      for (int w = 0; w < 8; ++w) { s += redA[w * 16 + tid]; d += redB[w * 16 + tid]; }
      out[(size_t)(b0 + tid) * T_STEPS + t + 1] = d / s + bfc0;
    }
    __syncthreads();  // zb/z/red stable before next step
  }
}

extern "C" void kernel_launch(void* const* d_in, const int* in_sizes, int n_in,
                              void* d_out, int out_size, void* d_ws, size_t ws_size,
                              hipStream_t stream) {
  const float* y    = (const float*)d_in[0];
  const float* ts   = (const float*)d_in[1];
  const float* Wi   = (const float*)d_in[2];
  // d_in[3] = Wf: computed-but-unused in reference -> skipped
  const float* Wg   = (const float*)d_in[4];
  const float* Wo   = (const float*)d_in[5];
  const float* Wout = (const float*)d_in[6];
  const float* bout = (const float*)d_in[7];
  const float* Wfc  = (const float*)d_in[8];
  const float* bfc  = (const float*)d_in[9];
  float* out = (float*)d_out;

  char* ws = (char*)d_ws;
  ushort_t* Wcat2 = (ushort_t*)(ws);            // 1536*512*2 = 1572864
  ushort_t* WoutB = (ushort_t*)(ws + 1572864);  // 512*512*2  = 524288

  convw_kernel<<<1024, 256, 0, stream>>>(Wi, Wg, Wo, Wout, Wcat2, WoutB);
  persist_kernel<<<BATCH / ROWS, 512, 0, stream>>>(y, ts, bout, Wfc, bfc,
                                                   Wcat2, WoutB, out);
}